// Round 19
// baseline (314.693 us; speedup 1.0000x reference)
//
#include <hip/hip_runtime.h>

using f16 = _Float16;
typedef f16 f16x8 __attribute__((ext_vector_type(8)));
typedef f16 f16x4 __attribute__((ext_vector_type(4)));
typedef float f32x4 __attribute__((ext_vector_type(4)));

#define TOKENS 4096   // B*N
#define KD 2048       // 2*DIM  (GEMM inner dim, k = 2*dk + ck)
#define NQ 6144       // qkv cols: which*2048 + h*128 + d*2 + c
#define QKW 4128      // PADDED width of Q,K buffer (8256B row stride, non-pow2)
#define VTS 2064      // PADDED token stride of Vt (4128B, non-pow2)

__device__ __forceinline__ void gload_lds16(const void* g, void* l) {
  __builtin_amdgcn_global_load_lds(
      (__attribute__((address_space(1))) void*)(unsigned long long)g,
      (__attribute__((address_space(3))) void*)l, 16, 0, 0);
}

// ---------------- prep kernels (vectorized, G13) ----------------
__global__ __launch_bounds__(256) void cast_x_kernel(const float* __restrict__ x,
                                                     f16* __restrict__ X, int n8) {
  int i = blockIdx.x * 256 + threadIdx.x;
  if (i >= n8) return;
  const float4* p = (const float4*)x + (size_t)i * 2;
  float4 a = p[0], b = p[1];
  f16x8 v = {(f16)a.x, (f16)a.y, (f16)a.z, (f16)a.w,
             (f16)b.x, (f16)b.y, (f16)b.z, (f16)b.w};
  *(f16x8*)(X + (size_t)i * 8) = v;
}

// Wp[j][k]: j = which*2048 + h*128 + d*2 + c, k = 2*dk + ck; one thread = 8 k.
__global__ __launch_bounds__(256) void pack_wqkv_kernel(const float* __restrict__ wr,
    const float* __restrict__ wi, const float* __restrict__ br, const float* __restrict__ bi,
    f16* __restrict__ Wp, float* __restrict__ biasq) {
  int idx = blockIdx.x * 256 + threadIdx.x;
  if (idx >= NQ * 256) return;
  int j = idx >> 8, kc = idx & 255;
  int which = j >> 11, rem = j & 2047;
  int h = rem >> 7, t = rem & 127, d = t >> 1, c = t & 1;
  int o = which * 1024 + h * 64 + d;
  const float4 wr4 = *(const float4*)(wr + (size_t)o * 1024 + kc * 4);
  const float4 wi4 = *(const float4*)(wi + (size_t)o * 1024 + kc * 4);
  f16x8 v;
  const float wrs[4] = {wr4.x, wr4.y, wr4.z, wr4.w};
  const float wis[4] = {wi4.x, wi4.y, wi4.z, wi4.w};
  #pragma unroll
  for (int tt = 0; tt < 4; ++tt) {
    v[2 * tt]     = (f16)((c == 0) ? wrs[tt] : wis[tt]);
    v[2 * tt + 1] = (f16)((c == 0) ? -wis[tt] : wrs[tt]);
  }
  *(f16x8*)(Wp + (size_t)j * KD + kc * 8) = v;
  if (kc == 0) biasq[j] = (c == 0) ? (br[o] - bi[o]) : (br[o] + bi[o]);
}

__global__ __launch_bounds__(256) void pack_wo_kernel(const float* __restrict__ wr,
    const float* __restrict__ wi, const float* __restrict__ br, const float* __restrict__ bi,
    f16* __restrict__ Wp, float* __restrict__ biaso) {
  int idx = blockIdx.x * 256 + threadIdx.x;
  if (idx >= KD * 256) return;
  int j = idx >> 8, kc = idx & 255;
  int jo = j >> 1, c = j & 1;
  const float4 wr4 = *(const float4*)(wr + (size_t)jo * 1024 + kc * 4);
  const float4 wi4 = *(const float4*)(wi + (size_t)jo * 1024 + kc * 4);
  f16x8 v;
  const float wrs[4] = {wr4.x, wr4.y, wr4.z, wr4.w};
  const float wis[4] = {wi4.x, wi4.y, wi4.z, wi4.w};
  #pragma unroll
  for (int tt = 0; tt < 4; ++tt) {
    v[2 * tt]     = (f16)((c == 0) ? wrs[tt] : wis[tt]);
    v[2 * tt + 1] = (f16)((c == 0) ? -wis[tt] : wrs[tt]);
  }
  *(f16x8*)(Wp + (size_t)j * KD + kc * 8) = v;
  if (kc == 0) biaso[j] = (c == 0) ? (br[jo] - bi[jo]) : (br[jo] + bi[jo]);
}

// ---------------- GEMM v5: m97 2-phase structure + swizzle + BK=64 ------------
// 128x128 tile, 4 waves (2x2), single-buffered 32KB LDS -> 3 blocks/CU
// (inter-block overlap hides barrier drains, m114).  T2 chunk-XOR swizzle.
template<bool QKV, int NTN>
__global__ __launch_bounds__(256, 3) void gemm_v5(const f16* __restrict__ A,
    const f16* __restrict__ B, const float* __restrict__ bias,
    f16* __restrict__ qkout, f16* __restrict__ vt, float* __restrict__ fout) {
  __shared__ __align__(16) f16 lA[128 * 64];  // 16 KiB
  __shared__ __align__(16) f16 lB[128 * 64];  // 16 KiB

  const int tid = threadIdx.x;
  const int wave = tid >> 6, lane = tid & 63;
  const int lo = lane & 15, hi = lane >> 4;
  const int wm = wave >> 1, wn = wave & 1;

  const int nwg = gridDim.x, cpx = nwg / 8;
  const int bid = blockIdx.x;
  const int wg = (bid & 7) * cpx + (bid >> 3);
  const int tm = wg / NTN, tn = wg % NTN;
  const int m0 = tm * 128, n0 = tn * 128;

  const f16* gA = A + (size_t)m0 * KD;
  const f16* gB = B + (size_t)n0 * KD;

  auto stage = [&](f16* ldsX, const f16* g) {
    #pragma unroll
    for (int is = 0; is < 4; ++is) {
      const int L = is * 256 + tid;
      const int row = L >> 3, cp = L & 7;
      gload_lds16(g + (size_t)row * KD + ((cp ^ (row & 7)) * 8),
                  ldsX + (size_t)(is * 256 + wave * 64) * 8);
    }
  };
  auto readA = [&](f16x8* dst, int kk) {
    #pragma unroll
    for (int i = 0; i < 4; ++i) {
      const int row = wm * 64 + i * 16 + lo;
      const int ch = (kk * 4 + hi) ^ (row & 7);
      dst[i] = *(const f16x8*)&lA[row * 64 + ch * 8];
    }
  };
  auto readB = [&](f16x8* dst, int kk) {
    #pragma unroll
    for (int i = 0; i < 4; ++i) {
      const int row = wn * 64 + i * 16 + lo;
      const int ch = (kk * 4 + hi) ^ (row & 7);
      dst[i] = *(const f16x8*)&lB[row * 64 + ch * 8];
    }
  };

  f32x4 acc[4][4] = {};

  for (int kt = 0; kt < KD; kt += 64) {
    __syncthreads();
    stage(lA, gA + kt);
    stage(lB, gB + kt);
    __syncthreads();
    f16x8 a[4], b[4];
    readA(a, 0); readB(b, 0);
    #pragma unroll
    for (int mi = 0; mi < 4; ++mi)
      #pragma unroll
      for (int ni = 0; ni < 4; ++ni)
        acc[mi][ni] = __builtin_amdgcn_mfma_f32_16x16x32_f16(a[mi], b[ni], acc[mi][ni], 0, 0, 0);
    readA(a, 1); readB(b, 1);
    #pragma unroll
    for (int mi = 0; mi < 4; ++mi)
      #pragma unroll
      for (int ni = 0; ni < 4; ++ni)
        acc[mi][ni] = __builtin_amdgcn_mfma_f32_16x16x32_f16(a[mi], b[ni], acc[mi][ni], 0, 0, 0);
  }

  #pragma unroll
  for (int mi = 0; mi < 4; ++mi) {
    #pragma unroll
    for (int ni = 0; ni < 4; ++ni) {
      const int colbase = n0 + wn * 64 + ni * 16;
      const int col = colbase + lo;
      const float bv = bias[col];
      const int rowb = m0 + wm * 64 + mi * 16 + hi * 4;
      if (QKV && colbase >= 4096) {
        const int dcol = col - 4096;
        const int hh = dcol >> 7, dd = dcol & 127;
        const int bb = rowb >> 11, tok = rowb & 2047;
        f16x4 pk;
        #pragma unroll
        for (int r = 0; r < 4; ++r) pk[r] = (f16)(acc[mi][ni][r] + bv);
        *(f16x4*)(vt + ((size_t)(bb * 16 + hh) * 128 + dd) * VTS + tok) = pk;
      } else if (QKV) {
        #pragma unroll
        for (int r = 0; r < 4; ++r)
          qkout[(size_t)(rowb + r) * QKW + col] = (f16)(acc[mi][ni][r] + bv);
      } else {
        #pragma unroll
        for (int r = 0; r < 4; ++r)
          fout[(size_t)(rowb + r) * KD + col] = acc[mi][ni][r] + bv;
      }
    }
  }
}

// ---------------- flash attention v12: R18 (full-rate PV) + exp2 softmax ------
// Block = 4 waves, 128 q-rows of one (b,h); wave = 32 q (qb=0,1).  KVBLK=32,
// 32KB double-buffered LDS, grid 512, full-group V swizzle, K=32 PV (R18,
// best: 127.6us).  ONLY change vs R18: softmax in exp2 domain — 0.125*log2(e)
// folded into the Q-scale constant, __expf -> __builtin_exp2f (drops the
// hidden x log2e v_mul inside each expf), defer threshold 8 nats -> 11.5
// (log2-equivalent; P <= 2^11.5 f16-safe).  Register-neutral by construction.
__global__ __launch_bounds__(256) void attn_kernel(const f16* __restrict__ qk,
                                                   const f16* __restrict__ vt,
                                                   f16* __restrict__ outp) {
  __shared__ __align__(16) f16 lds[2][8192];  // per buf: K [0,4096), V [4096,8192)
  const int tid = threadIdx.x;
  const int wave = tid >> 6, lane = tid & 63;
  const int lo = lane & 15, hi = lane >> 4;

  const int flat = blockIdx.x;
  const int nf = (flat & 7) * 64 + (flat >> 3);
  const int by = nf >> 4, bx = nf & 15;
  const int b = by >> 4, h = by & 15;
  const int q0 = bx * 128 + wave * 32;

  const f16* Qb = qk + (size_t)b * 2048 * QKW + h * 128;
  const f16* Kb = Qb + 2048;
  const f16* Vtb = vt + (size_t)(b * 16 + h) * 128 * VTS;

  f16x8 qf[2][4];
  #pragma unroll
  for (int qb = 0; qb < 2; ++qb)
    #pragma unroll
    for (int c = 0; c < 4; ++c) {
      qf[qb][c] = *(const f16x8*)(Qb + (size_t)(q0 + qb * 16 + lo) * QKW + c * 32 + hi * 8);
      qf[qb][c] *= (f16)0.18033688f;   // 0.125 * log2(e): softmax in exp2 domain
    }

  f32x4 o[2][8];
  #pragma unroll
  for (int qb = 0; qb < 2; ++qb)
    #pragma unroll
    for (int dc = 0; dc < 8; ++dc) o[qb][dc] = (f32x4){0.f, 0.f, 0.f, 0.f};
  float m_run[2] = {-INFINITY, -INFINITY};
  float l_run[2] = {0.f, 0.f};

  auto STAGE = [&](int buf, int t) {
    #pragma unroll
    for (int rnd = 0; rnd < 2; ++rnd) {
      const int cl = rnd * 256 + wave * 64 + lane;
      const int row = cl >> 4;
      const int gch = (cl & 15) ^ (row & 7);
      gload_lds16(Kb + (size_t)(t + row) * QKW + gch * 8,
                  &lds[buf][(size_t)(rnd * 256 + wave * 64) * 8]);
    }
    // V: physical chunk cl holds logical (d, j) with full-group XOR swizzle.
    #pragma unroll
    for (int rnd = 0; rnd < 2; ++rnd) {
      const int cl = rnd * 256 + wave * 64 + lane;
      const int grp = cl >> 3;
      const int q = (cl & 7) ^ (grp & 7);
      const int d = (grp << 1) | (q >> 2);
      const int j = q & 3;
      gload_lds16(Vtb + (size_t)d * VTS + t + j * 8,
                  &lds[buf][4096 + (size_t)(rnd * 256 + wave * 64) * 8]);
    }
  };

  STAGE(0, 0);
  int cur = 0;

  for (int it = 0; it < 64; ++it) {
    __syncthreads();                 // lds[cur] ready (vmcnt drained); prev reads done
    if (it + 1 < 64) STAGE(cur ^ 1, (it + 1) * 32);

    const f16* ldsK = lds[cur];
    const f16* ldsV = lds[cur] + 4096;

    f16x8 kf[2][4];
    #pragma unroll
    for (int tt = 0; tt < 2; ++tt)
      #pragma unroll
      for (int c = 0; c < 4; ++c) {
        const int row = tt * 16 + lo;
        const int ch = (c * 4 + hi) ^ (row & 7);
        kf[tt][c] = *(const f16x8*)&ldsK[row * 128 + ch * 8];
      }

    f16x8 pf8[2];
    #pragma unroll
    for (int qb = 0; qb < 2; ++qb) {
      f32x4 s0 = {0.f, 0.f, 0.f, 0.f}, s1 = {0.f, 0.f, 0.f, 0.f};
      #pragma unroll
      for (int c = 0; c < 4; ++c) {
        s0 = __builtin_amdgcn_mfma_f32_16x16x32_f16(kf[0][c], qf[qb][c], s0, 0, 0, 0);
        s1 = __builtin_amdgcn_mfma_f32_16x16x32_f16(kf[1][c], qf[qb][c], s1, 0, 0, 0);
      }

      float pm = fmaxf(fmaxf(fmaxf(s0[0], s0[1]), fmaxf(s0[2], s0[3])),
                       fmaxf(fmaxf(s1[0], s1[1]), fmaxf(s1[2], s1[3])));
      pm = fmaxf(pm, __shfl_xor(pm, 16));
      pm = fmaxf(pm, __shfl_xor(pm, 32));

      if (!__all(pm - m_run[qb] <= 11.5f)) {   // defer-max (T13), log2 domain
        const float corr = __builtin_exp2f(m_run[qb] - pm);
        m_run[qb] = pm;
        float co[4];
        #pragma unroll
        for (int r = 0; r < 4; ++r) co[r] = __shfl(corr, hi * 4 + r);
        #pragma unroll
        for (int dc = 0; dc < 8; ++dc)
          #pragma unroll
          for (int r = 0; r < 4; ++r) o[qb][dc][r] *= co[r];
        l_run[qb] *= corr;
      }

      float psum = 0.f;
      #pragma unroll
      for (int r = 0; r < 4; ++r) {
        const float p0 = __builtin_exp2f(s0[r] - m_run[qb]);
        const float p1 = __builtin_exp2f(s1[r] - m_run[qb]);
        psum += p0 + p1;
        pf8[qb][r]     = (f16)p0;   // tokens 4*hi + r
        pf8[qb][4 + r] = (f16)p1;   // tokens 16 + 4*hi + r
      }
      psum += __shfl_xor(psum, 16);
      psum += __shfl_xor(psum, 32);
      l_run[qb] += psum;
    }

    // vf read: same two b64 reads as R15, packed into one f16x8 (B-fragment
    // with the same (hi,j)->token map as pf8).  Full-rate K=32 PV.
    #pragma unroll
    for (int dc = 0; dc < 8; ++dc) {
      const int d = dc * 16 + lo;
      const int grp = d >> 1;
      f16x8 vf8;
      f16x4* pv = (f16x4*)&vf8;
      #pragma unroll
      for (int tt = 0; tt < 2; ++tt) {
        const int q = ((d & 1) << 2) | (2 * tt + (hi >> 1));
        const int qp = q ^ (grp & 7);
        pv[tt] = *(const f16x4*)&ldsV[grp * 64 + qp * 8 + (hi & 1) * 4];
      }
      o[0][dc] = __builtin_amdgcn_mfma_f32_16x16x32_f16(pf8[0], vf8, o[0][dc], 0, 0, 0);
      o[1][dc] = __builtin_amdgcn_mfma_f32_16x16x32_f16(pf8[1], vf8, o[1][dc], 0, 0, 0);
    }

    cur ^= 1;
  }

  #pragma unroll
  for (int qb = 0; qb < 2; ++qb) {
    float inv[4];
    #pragma unroll
    for (int r = 0; r < 4; ++r) inv[r] = 1.f / __shfl(l_run[qb], hi * 4 + r);
    const int tok0 = b * 2048 + q0 + qb * 16;
    #pragma unroll
    for (int dc = 0; dc < 8; ++dc)
      #pragma unroll
      for (int r = 0; r < 4; ++r)
        outp[(size_t)(tok0 + hi * 4 + r) * KD + h * 128 + dc * 16 + lo] =
            (f16)(o[qb][dc][r] * inv[r]);
  }
}

// ---------------- launch ----------------
extern "C" void kernel_launch(void* const* d_in, const int* in_sizes, int n_in,
                              void* d_out, int out_size, void* d_ws, size_t ws_size,
                              hipStream_t stream) {
  const float* x      = (const float*)d_in[0];
  const float* wqkv_r = (const float*)d_in[1];
  const float* wqkv_i = (const float*)d_in[2];
  const float* bqkv_r = (const float*)d_in[3];
  const float* bqkv_i = (const float*)d_in[4];
  const float* wo_r   = (const float*)d_in[5];
  const float* wo_i   = (const float*)d_in[6];
  const float* bo_r   = (const float*)d_in[7];
  const float* bo_i   = (const float*)d_in[8];
  float* out = (float*)d_out;
  char* ws = (char*)d_ws;

  f16*   Wqkv_p = (f16*)(ws + 0);              // 6144*2048*2    = 25165824
  f16*   Wo_p   = (f16*)(ws + 25165824);       // 2048*2048*2    =  8388608
  float* biasq  = (float*)(ws + 33554432);     // 6144*4
  float* biaso  = (float*)(ws + 33579008);     // 2048*4
  f16*   qkQK   = (f16*)(ws + 33587200);       // 4096*4128*2    = 33816576 (Q,K padded)
  f16*   Vt     = (f16*)(ws + 67403776);       // 32*128*2064*2  = 16908288 (V^T padded)
  f16*   Xh     = (f16*)(ws + 84312064);       // 4096*2048*2    = 16777216
  f16*   attn16 = Xh;                          // alias: X dead after GEMM1

  cast_x_kernel<<<(TOKENS * KD / 8) / 256, 256, 0, stream>>>(x, Xh, TOKENS * KD / 8);
  pack_wqkv_kernel<<<(NQ * 256) / 256, 256, 0, stream>>>(wqkv_r, wqkv_i, bqkv_r, bqkv_i,
                                                         Wqkv_p, biasq);
  pack_wo_kernel<<<(KD * 256) / 256, 256, 0, stream>>>(wo_r, wo_i, bo_r, bo_i, Wo_p, biaso);

  gemm_v5<true, 48><<<1536, 256, 0, stream>>>(Xh, Wqkv_p, biasq, qkQK, Vt, nullptr);
  attn_kernel<<<512, 256, 0, stream>>>(qkQK, Vt, attn16);
  gemm_v5<false, 16><<<512, 256, 0, stream>>>(attn16, Wo_p, biaso, nullptr, nullptr, out);
}

// Round 20
// 308.298 us; speedup vs baseline: 1.0207x; 1.0207x over previous
//
#include <hip/hip_runtime.h>

using f16 = _Float16;
typedef f16 f16x8 __attribute__((ext_vector_type(8)));
typedef f16 f16x4 __attribute__((ext_vector_type(4)));
typedef float f32x4 __attribute__((ext_vector_type(4)));

#define TOKENS 4096   // B*N
#define KD 2048       // 2*DIM  (GEMM inner dim, k = 2*dk + ck)
#define NQ 6144       // qkv cols: which*2048 + h*128 + d*2 + c
#define QKW 4128      // PADDED width of Q,K buffer (8256B row stride, non-pow2)
#define VTS 2064      // PADDED token stride of Vt (4128B, non-pow2)

__device__ __forceinline__ void gload_lds16(const void* g, void* l) {
  __builtin_amdgcn_global_load_lds(
      (__attribute__((address_space(1))) void*)(unsigned long long)g,
      (__attribute__((address_space(3))) void*)l, 16, 0, 0);
}

// ---------------- prep kernels (vectorized, G13) ----------------
__global__ __launch_bounds__(256) void cast_x_kernel(const float* __restrict__ x,
                                                     f16* __restrict__ X, int n8) {
  int i = blockIdx.x * 256 + threadIdx.x;
  if (i >= n8) return;
  const float4* p = (const float4*)x + (size_t)i * 2;
  float4 a = p[0], b = p[1];
  f16x8 v = {(f16)a.x, (f16)a.y, (f16)a.z, (f16)a.w,
             (f16)b.x, (f16)b.y, (f16)b.z, (f16)b.w};
  *(f16x8*)(X + (size_t)i * 8) = v;
}

// Wp[j][k]: j = which*2048 + h*128 + d*2 + c, k = 2*dk + ck; one thread = 8 k.
__global__ __launch_bounds__(256) void pack_wqkv_kernel(const float* __restrict__ wr,
    const float* __restrict__ wi, const float* __restrict__ br, const float* __restrict__ bi,
    f16* __restrict__ Wp, float* __restrict__ biasq) {
  int idx = blockIdx.x * 256 + threadIdx.x;
  if (idx >= NQ * 256) return;
  int j = idx >> 8, kc = idx & 255;
  int which = j >> 11, rem = j & 2047;
  int h = rem >> 7, t = rem & 127, d = t >> 1, c = t & 1;
  int o = which * 1024 + h * 64 + d;
  const float4 wr4 = *(const float4*)(wr + (size_t)o * 1024 + kc * 4);
  const float4 wi4 = *(const float4*)(wi + (size_t)o * 1024 + kc * 4);
  f16x8 v;
  const float wrs[4] = {wr4.x, wr4.y, wr4.z, wr4.w};
  const float wis[4] = {wi4.x, wi4.y, wi4.z, wi4.w};
  #pragma unroll
  for (int tt = 0; tt < 4; ++tt) {
    v[2 * tt]     = (f16)((c == 0) ? wrs[tt] : wis[tt]);
    v[2 * tt + 1] = (f16)((c == 0) ? -wis[tt] : wrs[tt]);
  }
  *(f16x8*)(Wp + (size_t)j * KD + kc * 8) = v;
  if (kc == 0) biasq[j] = (c == 0) ? (br[o] - bi[o]) : (br[o] + bi[o]);
}

__global__ __launch_bounds__(256) void pack_wo_kernel(const float* __restrict__ wr,
    const float* __restrict__ wi, const float* __restrict__ br, const float* __restrict__ bi,
    f16* __restrict__ Wp, float* __restrict__ biaso) {
  int idx = blockIdx.x * 256 + threadIdx.x;
  if (idx >= KD * 256) return;
  int j = idx >> 8, kc = idx & 255;
  int jo = j >> 1, c = j & 1;
  const float4 wr4 = *(const float4*)(wr + (size_t)jo * 1024 + kc * 4);
  const float4 wi4 = *(const float4*)(wi + (size_t)jo * 1024 + kc * 4);
  f16x8 v;
  const float wrs[4] = {wr4.x, wr4.y, wr4.z, wr4.w};
  const float wis[4] = {wi4.x, wi4.y, wi4.z, wi4.w};
  #pragma unroll
  for (int tt = 0; tt < 4; ++tt) {
    v[2 * tt]     = (f16)((c == 0) ? wrs[tt] : wis[tt]);
    v[2 * tt + 1] = (f16)((c == 0) ? -wis[tt] : wrs[tt]);
  }
  *(f16x8*)(Wp + (size_t)j * KD + kc * 8) = v;
  if (kc == 0) biaso[j] = (c == 0) ? (br[jo] - bi[jo]) : (br[jo] + bi[jo]);
}

// ---------------- GEMM v5: m97 2-phase structure + swizzle + BK=64 ------------
// 128x128 tile, 4 waves (2x2), single-buffered 32KB LDS -> 3 blocks/CU
// (inter-block overlap hides barrier drains, m114).  T2 chunk-XOR swizzle.
template<bool QKV, int NTN>
__global__ __launch_bounds__(256, 3) void gemm_v5(const f16* __restrict__ A,
    const f16* __restrict__ B, const float* __restrict__ bias,
    f16* __restrict__ qkout, f16* __restrict__ vt, float* __restrict__ fout) {
  __shared__ __align__(16) f16 lA[128 * 64];  // 16 KiB
  __shared__ __align__(16) f16 lB[128 * 64];  // 16 KiB

  const int tid = threadIdx.x;
  const int wave = tid >> 6, lane = tid & 63;
  const int lo = lane & 15, hi = lane >> 4;
  const int wm = wave >> 1, wn = wave & 1;

  const int nwg = gridDim.x, cpx = nwg / 8;
  const int bid = blockIdx.x;
  const int wg = (bid & 7) * cpx + (bid >> 3);
  const int tm = wg / NTN, tn = wg % NTN;
  const int m0 = tm * 128, n0 = tn * 128;

  const f16* gA = A + (size_t)m0 * KD;
  const f16* gB = B + (size_t)n0 * KD;

  auto stage = [&](f16* ldsX, const f16* g) {
    #pragma unroll
    for (int is = 0; is < 4; ++is) {
      const int L = is * 256 + tid;
      const int row = L >> 3, cp = L & 7;
      gload_lds16(g + (size_t)row * KD + ((cp ^ (row & 7)) * 8),
                  ldsX + (size_t)(is * 256 + wave * 64) * 8);
    }
  };
  auto readA = [&](f16x8* dst, int kk) {
    #pragma unroll
    for (int i = 0; i < 4; ++i) {
      const int row = wm * 64 + i * 16 + lo;
      const int ch = (kk * 4 + hi) ^ (row & 7);
      dst[i] = *(const f16x8*)&lA[row * 64 + ch * 8];
    }
  };
  auto readB = [&](f16x8* dst, int kk) {
    #pragma unroll
    for (int i = 0; i < 4; ++i) {
      const int row = wn * 64 + i * 16 + lo;
      const int ch = (kk * 4 + hi) ^ (row & 7);
      dst[i] = *(const f16x8*)&lB[row * 64 + ch * 8];
    }
  };

  f32x4 acc[4][4] = {};

  for (int kt = 0; kt < KD; kt += 64) {
    __syncthreads();
    stage(lA, gA + kt);
    stage(lB, gB + kt);
    __syncthreads();
    f16x8 a[4], b[4];
    readA(a, 0); readB(b, 0);
    #pragma unroll
    for (int mi = 0; mi < 4; ++mi)
      #pragma unroll
      for (int ni = 0; ni < 4; ++ni)
        acc[mi][ni] = __builtin_amdgcn_mfma_f32_16x16x32_f16(a[mi], b[ni], acc[mi][ni], 0, 0, 0);
    readA(a, 1); readB(b, 1);
    #pragma unroll
    for (int mi = 0; mi < 4; ++mi)
      #pragma unroll
      for (int ni = 0; ni < 4; ++ni)
        acc[mi][ni] = __builtin_amdgcn_mfma_f32_16x16x32_f16(a[mi], b[ni], acc[mi][ni], 0, 0, 0);
  }

  #pragma unroll
  for (int mi = 0; mi < 4; ++mi) {
    #pragma unroll
    for (int ni = 0; ni < 4; ++ni) {
      const int colbase = n0 + wn * 64 + ni * 16;
      const int col = colbase + lo;
      const float bv = bias[col];
      const int rowb = m0 + wm * 64 + mi * 16 + hi * 4;
      if (QKV && colbase >= 4096) {
        const int dcol = col - 4096;
        const int hh = dcol >> 7, dd = dcol & 127;
        const int bb = rowb >> 11, tok = rowb & 2047;
        f16x4 pk;
        #pragma unroll
        for (int r = 0; r < 4; ++r) pk[r] = (f16)(acc[mi][ni][r] + bv);
        *(f16x4*)(vt + ((size_t)(bb * 16 + hh) * 128 + dd) * VTS + tok) = pk;
      } else if (QKV) {
        #pragma unroll
        for (int r = 0; r < 4; ++r)
          qkout[(size_t)(rowb + r) * QKW + col] = (f16)(acc[mi][ni][r] + bv);
      } else {
        #pragma unroll
        for (int r = 0; r < 4; ++r)
          fout[(size_t)(rowb + r) * KD + col] = acc[mi][ni][r] + bv;
      }
    }
  }
}

// ---------------- flash attention v11 (R18, session best): full-rate PV -------
// Block = 4 waves, 128 q-rows of one (b,h); wave = 32 q (qb=0,1).  KVBLK=32,
// 32KB double-buffered LDS, grid 512, full-group V swizzle.  PV uses
// mfma_f32_16x16x32_f16 (full rate): pf8 = pf0||pf1 and vf8 = vf0||vf1 assign
// token (j<4 ? 4*hi+j : 16+4*hi+j-4) identically on A and B, so the K=32
// contraction is exact.  VGPR 124 (under the 128 residency cliff).
__global__ __launch_bounds__(256) void attn_kernel(const f16* __restrict__ qk,
                                                   const f16* __restrict__ vt,
                                                   f16* __restrict__ outp) {
  __shared__ __align__(16) f16 lds[2][8192];  // per buf: K [0,4096), V [4096,8192)
  const int tid = threadIdx.x;
  const int wave = tid >> 6, lane = tid & 63;
  const int lo = lane & 15, hi = lane >> 4;

  const int flat = blockIdx.x;
  const int nf = (flat & 7) * 64 + (flat >> 3);
  const int by = nf >> 4, bx = nf & 15;
  const int b = by >> 4, h = by & 15;
  const int q0 = bx * 128 + wave * 32;

  const f16* Qb = qk + (size_t)b * 2048 * QKW + h * 128;
  const f16* Kb = Qb + 2048;
  const f16* Vtb = vt + (size_t)(b * 16 + h) * 128 * VTS;

  f16x8 qf[2][4];
  #pragma unroll
  for (int qb = 0; qb < 2; ++qb)
    #pragma unroll
    for (int c = 0; c < 4; ++c) {
      qf[qb][c] = *(const f16x8*)(Qb + (size_t)(q0 + qb * 16 + lo) * QKW + c * 32 + hi * 8);
      qf[qb][c] *= (f16)0.125f;
    }

  f32x4 o[2][8];
  #pragma unroll
  for (int qb = 0; qb < 2; ++qb)
    #pragma unroll
    for (int dc = 0; dc < 8; ++dc) o[qb][dc] = (f32x4){0.f, 0.f, 0.f, 0.f};
  float m_run[2] = {-INFINITY, -INFINITY};
  float l_run[2] = {0.f, 0.f};

  auto STAGE = [&](int buf, int t) {
    #pragma unroll
    for (int rnd = 0; rnd < 2; ++rnd) {
      const int cl = rnd * 256 + wave * 64 + lane;
      const int row = cl >> 4;
      const int gch = (cl & 15) ^ (row & 7);
      gload_lds16(Kb + (size_t)(t + row) * QKW + gch * 8,
                  &lds[buf][(size_t)(rnd * 256 + wave * 64) * 8]);
    }
    // V: physical chunk cl holds logical (d, j) with full-group XOR swizzle.
    #pragma unroll
    for (int rnd = 0; rnd < 2; ++rnd) {
      const int cl = rnd * 256 + wave * 64 + lane;
      const int grp = cl >> 3;
      const int q = (cl & 7) ^ (grp & 7);
      const int d = (grp << 1) | (q >> 2);
      const int j = q & 3;
      gload_lds16(Vtb + (size_t)d * VTS + t + j * 8,
                  &lds[buf][4096 + (size_t)(rnd * 256 + wave * 64) * 8]);
    }
  };

  STAGE(0, 0);
  int cur = 0;

  for (int it = 0; it < 64; ++it) {
    __syncthreads();                 // lds[cur] ready (vmcnt drained); prev reads done
    if (it + 1 < 64) STAGE(cur ^ 1, (it + 1) * 32);

    const f16* ldsK = lds[cur];
    const f16* ldsV = lds[cur] + 4096;

    f16x8 kf[2][4];
    #pragma unroll
    for (int tt = 0; tt < 2; ++tt)
      #pragma unroll
      for (int c = 0; c < 4; ++c) {
        const int row = tt * 16 + lo;
        const int ch = (c * 4 + hi) ^ (row & 7);
        kf[tt][c] = *(const f16x8*)&ldsK[row * 128 + ch * 8];
      }

    f16x8 pf8[2];
    #pragma unroll
    for (int qb = 0; qb < 2; ++qb) {
      f32x4 s0 = {0.f, 0.f, 0.f, 0.f}, s1 = {0.f, 0.f, 0.f, 0.f};
      #pragma unroll
      for (int c = 0; c < 4; ++c) {
        s0 = __builtin_amdgcn_mfma_f32_16x16x32_f16(kf[0][c], qf[qb][c], s0, 0, 0, 0);
        s1 = __builtin_amdgcn_mfma_f32_16x16x32_f16(kf[1][c], qf[qb][c], s1, 0, 0, 0);
      }

      float pm = fmaxf(fmaxf(fmaxf(s0[0], s0[1]), fmaxf(s0[2], s0[3])),
                       fmaxf(fmaxf(s1[0], s1[1]), fmaxf(s1[2], s1[3])));
      pm = fmaxf(pm, __shfl_xor(pm, 16));
      pm = fmaxf(pm, __shfl_xor(pm, 32));

      if (!__all(pm - m_run[qb] <= 8.f)) {   // defer-max (T13)
        const float corr = __expf(m_run[qb] - pm);
        m_run[qb] = pm;
        float co[4];
        #pragma unroll
        for (int r = 0; r < 4; ++r) co[r] = __shfl(corr, hi * 4 + r);
        #pragma unroll
        for (int dc = 0; dc < 8; ++dc)
          #pragma unroll
          for (int r = 0; r < 4; ++r) o[qb][dc][r] *= co[r];
        l_run[qb] *= corr;
      }

      float psum = 0.f;
      #pragma unroll
      for (int r = 0; r < 4; ++r) {
        const float p0 = __expf(s0[r] - m_run[qb]);
        const float p1 = __expf(s1[r] - m_run[qb]);
        psum += p0 + p1;
        pf8[qb][r]     = (f16)p0;   // tokens 4*hi + r
        pf8[qb][4 + r] = (f16)p1;   // tokens 16 + 4*hi + r
      }
      psum += __shfl_xor(psum, 16);
      psum += __shfl_xor(psum, 32);
      l_run[qb] += psum;
    }

    // vf read: same two b64 reads as R15, packed into one f16x8 (B-fragment
    // with the same (hi,j)->token map as pf8).  Full-rate K=32 PV.
    #pragma unroll
    for (int dc = 0; dc < 8; ++dc) {
      const int d = dc * 16 + lo;
      const int grp = d >> 1;
      f16x8 vf8;
      f16x4* pv = (f16x4*)&vf8;
      #pragma unroll
      for (int tt = 0; tt < 2; ++tt) {
        const int q = ((d & 1) << 2) | (2 * tt + (hi >> 1));
        const int qp = q ^ (grp & 7);
        pv[tt] = *(const f16x4*)&ldsV[grp * 64 + qp * 8 + (hi & 1) * 4];
      }
      o[0][dc] = __builtin_amdgcn_mfma_f32_16x16x32_f16(pf8[0], vf8, o[0][dc], 0, 0, 0);
      o[1][dc] = __builtin_amdgcn_mfma_f32_16x16x32_f16(pf8[1], vf8, o[1][dc], 0, 0, 0);
    }

    cur ^= 1;
  }

  #pragma unroll
  for (int qb = 0; qb < 2; ++qb) {
    float inv[4];
    #pragma unroll
    for (int r = 0; r < 4; ++r) inv[r] = 1.f / __shfl(l_run[qb], hi * 4 + r);
    const int tok0 = b * 2048 + q0 + qb * 16;
    #pragma unroll
    for (int dc = 0; dc < 8; ++dc)
      #pragma unroll
      for (int r = 0; r < 4; ++r)
        outp[(size_t)(tok0 + hi * 4 + r) * KD + h * 128 + dc * 16 + lo] =
            (f16)(o[qb][dc][r] * inv[r]);
  }
}

// ---------------- launch ----------------
extern "C" void kernel_launch(void* const* d_in, const int* in_sizes, int n_in,
                              void* d_out, int out_size, void* d_ws, size_t ws_size,
                              hipStream_t stream) {
  const float* x      = (const float*)d_in[0];
  const float* wqkv_r = (const float*)d_in[1];
  const float* wqkv_i = (const float*)d_in[2];
  const float* bqkv_r = (const float*)d_in[3];
  const float* bqkv_i = (const float*)d_in[4];
  const float* wo_r   = (const float*)d_in[5];
  const float* wo_i   = (const float*)d_in[6];
  const float* bo_r   = (const float*)d_in[7];
  const float* bo_i   = (const float*)d_in[8];
  float* out = (float*)d_out;
  char* ws = (char*)d_ws;

  f16*   Wqkv_p = (f16*)(ws + 0);              // 6144*2048*2    = 25165824
  f16*   Wo_p   = (f16*)(ws + 25165824);       // 2048*2048*2    =  8388608
  float* biasq  = (float*)(ws + 33554432);     // 6144*4
  float* biaso  = (float*)(ws + 33579008);     // 2048*4
  f16*   qkQK   = (f16*)(ws + 33587200);       // 4096*4128*2    = 33816576 (Q,K padded)
  f16*   Vt     = (f16*)(ws + 67403776);       // 32*128*2064*2  = 16908288 (V^T padded)
  f16*   Xh     = (f16*)(ws + 84312064);       // 4096*2048*2    = 16777216
  f16*   attn16 = Xh;                          // alias: X dead after GEMM1

  cast_x_kernel<<<(TOKENS * KD / 8) / 256, 256, 0, stream>>>(x, Xh, TOKENS * KD / 8);
  pack_wqkv_kernel<<<(NQ * 256) / 256, 256, 0, stream>>>(wqkv_r, wqkv_i, bqkv_r, bqkv_i,
                                                         Wqkv_p, biasq);
  pack_wo_kernel<<<(KD * 256) / 256, 256, 0, stream>>>(wo_r, wo_i, bo_r, bo_i, Wo_p, biaso);

  gemm_v5<true, 48><<<1536, 256, 0, stream>>>(Xh, Wqkv_p, biasq, qkQK, Vt, nullptr);
  attn_kernel<<<512, 256, 0, stream>>>(qkQK, Vt, attn16);
  gemm_v5<false, 16><<<512, 256, 0, stream>>>(attn16, Wo_p, biaso, nullptr, nullptr, out);
}